// Round 2
// baseline (690.426 us; speedup 1.0000x reference)
//
#include <hip/hip_runtime.h>
#include <hip/hip_bf16.h>

#define NPOS 1296              // 36*36 oscillators
#define BATCH 512
#define STEPS 25
#define PH_STRIDE (BATCH * NPOS)            // 663552
#define PH_TOTAL ((STEPS + 1) * PH_STRIDE)  // 17252352
#define FC_K 3456
#define FC_N 864
#define FC_NPAD 896
#define KT_ITERS 54            // FC_K / 64
#define NBLK 512
#define NTHR 256

typedef float f32x4 __attribute__((ext_vector_type(4)));
typedef __bf16 bf16x8 __attribute__((ext_vector_type(8)));

__device__ __forceinline__ ushort f2bf(float f) {
  union { float f; unsigned u; } v; v.f = f;
  unsigned r = v.u + 0x7FFFu + ((v.u >> 16) & 1u);  // RNE
  return (ushort)(r >> 16);
}

__device__ __forceinline__ void async_copy16(void* lds, const void* g) {
  __builtin_amdgcn_global_load_lds(
      (const __attribute__((address_space(1))) unsigned*)g,
      (__attribute__((address_space(3))) unsigned*)lds, 16, 0, 0);
}
__device__ __forceinline__ void raw_barrier() { asm volatile("s_barrier" ::: "memory"); }
__device__ __forceinline__ void waitcnt_vm7() { asm volatile("s_waitcnt vmcnt(7)" ::: "memory"); }
__device__ __forceinline__ void waitcnt_vm0() { asm volatile("s_waitcnt vmcnt(0)" ::: "memory"); }

// Software grid barrier: 512 blocks are all co-resident by construction
// (LDS 57344 B -> exactly 2 blocks/CU x 256 CU = 512; VGPR capped by launch_bounds).
// Device-scope atomics are cross-XCD correct; __threadfence() emits the L2
// writeback/invalidate needed for cross-XCD visibility of plain stores.
__device__ __forceinline__ void grid_barrier(int* bar) {
  __threadfence();               // release: publish this block's global writes
  __syncthreads();
  if (threadIdx.x == 0) {
    __hip_atomic_fetch_add(bar, 1, __ATOMIC_RELEASE, __HIP_MEMORY_SCOPE_AGENT);
    while (__hip_atomic_load(bar, __ATOMIC_ACQUIRE, __HIP_MEMORY_SCOPE_AGENT) < NBLK)
      __builtin_amdgcn_s_sleep(2);
  }
  __syncthreads();
  __threadfence();               // acquire: invalidate caches before reads
}

// LDS union: gemm double-buffer (57344 B) dominates -> exactly 2 blocks/CU
struct ConvSh {
  float  sIn[18][40];          // 2880 B
  ushort sC1[18][40][8];       // 11520 B
  ushort sC2[16][40][16];      // 20480 B
  ushort w2t[16 * 96];         // 3072 B
  ushort w3t[32 * 160];        // 10240 B
};
union ShMem {
  ConvSh a;                    // 48192 B
  ushort g[2][14336];          // 57344 B (gemm tiles)
  float2 sc[2][NPOS];          // 20736 B (kuramoto sin/cos)
};

// One persistent kernel: stageA (prep + fcw->bf16 + conv x3 tasks)
//   -> grid barrier -> stageB (bf16 NT GEMM, blocks 0..447) -> grid barrier -> stageC (kuramoto).
__global__ __launch_bounds__(NTHR, 2) void megakernel(
    const float* __restrict__ in, const float* __restrict__ w1, const float* __restrict__ b1,
    const float* __restrict__ w2, const float* __restrict__ b2,
    const float* __restrict__ w3, const float* __restrict__ b3,
    const float* __restrict__ fcw, const float* __restrict__ fcb,
    const float* __restrict__ ph0, const int* __restrict__ conn,
    ushort* __restrict__ Abuf, ushort* __restrict__ Wbuf,
    int* __restrict__ bar, float* __restrict__ out) {
  __shared__ __align__(16) ShMem sh;
  const int tid = threadIdx.x, blk = blockIdx.x;
  const int wave = tid >> 6, lane = tid & 63;
  const int quad = lane >> 4, l16 = lane & 15;

  // ========================= stage A: prep + conv =========================
  {
    // fc_w f32 -> bf16, rows padded to 896 (grid-strided, coalesced)
    for (int idx = blk * NTHR + tid; idx < FC_NPAD * FC_K; idx += NBLK * NTHR) {
      const int n = idx / FC_K;
      Wbuf[idx] = (n < FC_N) ? f2bf(fcw[idx]) : (ushort)0;
    }
    // per-block conv2/conv3 weight transposes into LDS (MFMA [co][k] layout)
    for (int i = tid; i < 16 * 96; i += NTHR) {
      const int co = i / 96, k = i - co * 96, s = k >> 3, ci = k & 7;
      sh.a.w2t[i] = (k < 72) ? f2bf(w2[(co * 8 + ci) * 9 + s]) : (ushort)0;
    }
    for (int i = tid; i < 32 * 160; i += NTHR) {
      const int co = i / 160, k = i - co * 160, s = k >> 4, ci = k & 15;
      sh.a.w3t[i] = (k < 144) ? f2bf(w3[(co * 16 + ci) * 9 + s]) : (ushort)0;
    }
    __syncthreads();
    // hoist weight fragments + biases (persist across the 3 conv tasks)
    bf16x8 w2f[3];
#pragma unroll
    for (int f = 0; f < 3; ++f)
      w2f[f] = *(const bf16x8*)(sh.a.w2t + l16 * 96 + f * 32 + quad * 8);
    bf16x8 w3f[2][5];
#pragma unroll
    for (int t = 0; t < 2; ++t)
#pragma unroll
      for (int f = 0; f < 5; ++f)
        w3f[t][f] = *(const bf16x8*)(sh.a.w3t + (t * 16 + l16) * 160 + f * 32 + quad * 8);
    float b1v[8];
#pragma unroll
    for (int co = 0; co < 8; ++co) b1v[co] = b1[co];
    const float bias2 = b2[l16];
    const float bias3a = b3[l16], bias3b = b3[16 + l16];

    // 1536 (b, band) tasks over 512 blocks: task -> b = blk, band = 0,1,2
    for (int task = blk; task < 3 * BATCH; task += NBLK) {
      const int b = task & 511, band = task >> 9;
      const int r0 = band * 12;
      __syncthreads();  // prior task's LDS reads done
      {
        const uint4 zz = make_uint4(0, 0, 0, 0);
        for (int i = tid; i < 180; i += NTHR) ((uint4*)sh.a.sIn)[i] = zz;
        for (int i = tid; i < 720; i += NTHR) ((uint4*)sh.a.sC1)[i] = zz;
        for (int i = tid; i < 1280; i += NTHR) ((uint4*)sh.a.sC2)[i] = zz;
      }
      __syncthreads();
      for (int i = tid; i < 18 * 18; i += NTHR) {
        const int r = i / 18, c = i - r * 18;
        const int gy = r0 - 3 + r;
        if ((unsigned)gy < 36u)
          *(float2*)&sh.a.sIn[r][2 + 2 * c] = *(const float2*)(in + (size_t)b * NPOS + gy * 36 + 2 * c);
      }
      __syncthreads();
      // conv1 (VALU; w1 read with uniform address -> scalar loads)
      for (int i = tid; i < 16 * 36; i += NTHR) {
        const int lr = i / 36, x = i - lr * 36;
        float acc[8];
#pragma unroll
        for (int co = 0; co < 8; ++co) acc[co] = b1v[co];
#pragma unroll
        for (int s = 0; s < 9; ++s) {
          const int dy = s / 3, dx = s - 3 * dy;
          const float v = sh.a.sIn[lr + dy][x + 1 + dx];
#pragma unroll
          for (int co = 0; co < 8; ++co) acc[co] = fmaf(w1[co * 9 + s], v, acc[co]);
        }
        const int g1 = r0 - 2 + lr;
        if ((unsigned)g1 < 36u) {
          uint4 pk;
          pk.x = (uint)f2bf(fmaxf(acc[0], 0.f)) | ((uint)f2bf(fmaxf(acc[1], 0.f)) << 16);
          pk.y = (uint)f2bf(fmaxf(acc[2], 0.f)) | ((uint)f2bf(fmaxf(acc[3], 0.f)) << 16);
          pk.z = (uint)f2bf(fmaxf(acc[4], 0.f)) | ((uint)f2bf(fmaxf(acc[5], 0.f)) << 16);
          pk.w = (uint)f2bf(fmaxf(acc[6], 0.f)) | ((uint)f2bf(fmaxf(acc[7], 0.f)) << 16);
          *(uint4*)&sh.a.sC1[lr][x + 2][0] = pk;
        }
      }
      __syncthreads();
      // conv2 via MFMA: M=512 px, N=16 co, K=96 (72 real)
      for (int chunk = wave; chunk < 32; chunk += 4) {
        const int m = chunk * 16 + l16;
        const int oy = m / 36, x = m - oy * 36;
        f32x4 acc = {0.f, 0.f, 0.f, 0.f};
#pragma unroll
        for (int f = 0; f < 3; ++f) {
          const int s0 = 4 * f + quad;
          const int dy = s0 / 3, dx = s0 - 3 * dy;
          const bf16x8 af = *(const bf16x8*)&sh.a.sC1[oy + dy][x + 1 + dx][0];
          acc = __builtin_amdgcn_mfma_f32_16x16x32_bf16(af, w2f[f], acc, 0, 0, 0);
        }
#pragma unroll
        for (int r = 0; r < 4; ++r) {
          const int px = chunk * 16 + quad * 4 + r;
          const int oy2 = px / 36, x2 = px - oy2 * 36;
          const int g2 = r0 - 1 + oy2;
          if (px < 504 && (unsigned)g2 < 36u)
            sh.a.sC2[oy2][x2 + 2][l16] = f2bf(fmaxf(acc[r] + bias2, 0.f));
        }
      }
      __syncthreads();
      // conv3 via MFMA + sigmoid: M=432 px, N=32 co (2 tiles), K=160 (144 real)
      ushort* ob = Abuf + (size_t)b * (32 * NPOS) + r0 * 36;
      for (int chunk = wave; chunk < 27; chunk += 4) {
        const int m = chunk * 16 + l16;
        const int oy = m / 36, x = m - oy * 36;
        f32x4 acc0 = {0.f, 0.f, 0.f, 0.f}, acc1 = {0.f, 0.f, 0.f, 0.f};
#pragma unroll
        for (int f = 0; f < 5; ++f) {
          const int s0 = 2 * f + (quad >> 1);
          const int dy = s0 / 3, dx = s0 - 3 * dy;
          const bf16x8 af = *(const bf16x8*)&sh.a.sC2[oy + dy][x + 1 + dx][(quad & 1) * 8];
          acc0 = __builtin_amdgcn_mfma_f32_16x16x32_bf16(af, w3f[0][f], acc0, 0, 0, 0);
          acc1 = __builtin_amdgcn_mfma_f32_16x16x32_bf16(af, w3f[1][f], acc1, 0, 0, 0);
        }
        const int pxb = chunk * 16 + quad * 4;
        ushort4 pk;
#pragma unroll
        for (int r = 0; r < 4; ++r)
          ((ushort*)&pk)[r] = f2bf(1.f / (1.f + __expf(-(acc0[r] + bias3a))));
        *(ushort4*)(ob + (size_t)l16 * NPOS + pxb) = pk;
#pragma unroll
        for (int r = 0; r < 4; ++r)
          ((ushort*)&pk)[r] = f2bf(1.f / (1.f + __expf(-(acc1[r] + bias3b))));
        *(ushort4*)(ob + (size_t)(16 + l16) * NPOS + pxb) = pk;
      }
    }
  }
  grid_barrier(bar + 0);

  // ========================= stage B: bf16 NT GEMM =========================
  // C[m][n] = sum_k A[m][k]*Bt[n][k] + bias[n]; 96x128 tile, 4 waves of 48x64.
  // Double-buffered LDS, raw s_barrier + vmcnt(7) pipeline, XOR-swizzled cells.
  if (blk < 448) {
    const int xcd = blk & 7, grp = blk >> 3;
    const int bn = grp % 7;
    const int bm = xcd + 8 * (grp / 7);          // 0..63
    const int row0 = bm * 96, col0 = bn * 128;
    const int wr = (wave >> 1) * 48, wc = (wave & 1) * 64;
    const int oswz = (quad ^ ((l16 >> 1) & 3)) * 8;
    f32x4 acc[3][4] = {};

    const int rr = lane >> 2;                               // row within chunk
    const int soct = ((lane & 3) ^ ((lane >> 3) & 3)) * 8;  // source k-octet
    const ushort* gsrc[7];
    const ushort* ldst[7];
    {
      const int s = wave >> 1;  // slab this wave-pair stages
      if ((wave & 1) == 0) {
#pragma unroll
        for (int j = 0; j < 6; ++j) {
          gsrc[j] = Abuf + ((size_t)row0 + j * 16 + rr) * FC_K + s * 32 + soct;
          ldst[j] = &sh.g[0][s * 3072 + j * 512];
        }
        gsrc[6] = Wbuf + ((size_t)col0 + rr) * FC_K + s * 32 + soct;
        ldst[6] = &sh.g[0][6144 + s * 4096];
      } else {
#pragma unroll
        for (int j = 0; j < 7; ++j) {
          gsrc[j] = Wbuf + ((size_t)col0 + (j + 1) * 16 + rr) * FC_K + s * 32 + soct;
          ldst[j] = &sh.g[0][6144 + s * 4096 + (j + 1) * 512];
        }
      }
    }
#pragma unroll
    for (int j = 0; j < 7; ++j) async_copy16((void*)ldst[j], gsrc[j]);
#pragma unroll
    for (int j = 0; j < 7; ++j) async_copy16((void*)(ldst[j] + 14336), gsrc[j] + 64);

    for (int kt = 0; kt < KT_ITERS; ++kt) {
      const int p = kt & 1;
      waitcnt_vm7();
      raw_barrier();
      const ushort* base = &sh.g[p][0];
#pragma unroll
      for (int s = 0; s < 2; ++s) {
        bf16x8 af[3], bfr[4];
#pragma unroll
        for (int t = 0; t < 3; ++t)
          af[t] = *(const bf16x8*)(base + s * 3072 + (wr + t * 16 + l16) * 32 + oswz);
#pragma unroll
        for (int t = 0; t < 4; ++t)
          bfr[t] = *(const bf16x8*)(base + 6144 + s * 4096 + (wc + t * 16 + l16) * 32 + oswz);
#pragma unroll
        for (int tm = 0; tm < 3; ++tm)
#pragma unroll
          for (int tn = 0; tn < 4; ++tn)
            acc[tm][tn] = __builtin_amdgcn_mfma_f32_16x16x32_bf16(af[tm], bfr[tn], acc[tm][tn], 0, 0, 0);
      }
      raw_barrier();
      int kn = kt + 2;
      if (kn >= KT_ITERS) kn -= KT_ITERS;
      const int koff = kn * 64;
#pragma unroll
      for (int j = 0; j < 7; ++j) async_copy16((void*)(ldst[j] + p * 14336), gsrc[j] + koff);
    }
    waitcnt_vm0();

    float* C = out + PH_TOTAL;
#pragma unroll
    for (int tn = 0; tn < 4; ++tn) {
      const int col = col0 + wc + tn * 16 + l16;
      if (col < FC_N) {
        const float bv = fcb[col];
#pragma unroll
        for (int tm = 0; tm < 3; ++tm) {
#pragma unroll
          for (int r = 0; r < 4; ++r) {
            const int row = row0 + wr + tm * 16 + quad * 4 + r;
            C[(size_t)row * FC_N + col] = acc[tm][tn][r] + bv;
          }
        }
      }
    }
  }
  grid_barrier(bar + 1);

  // ========================= stage C: kuramoto =========================
  // One block per batch, 256 threads x 6 oscillator slots; state in registers,
  // double-buffered sin/cos in LDS -> one barrier per step.
  {
    const int b = blk;
    const float* cpl = out + PH_TOTAL;
    int rj[6][8];
    float rc[6][8];
    float myph[6];
    float2 mysc[6];
#pragma unroll
    for (int s = 0; s < 6; ++s) {
      const int i = tid + (s << 8);
      if (i < NPOS) {
        const float p = ph0[(size_t)b * NPOS + i];
        myph[s] = p;
        __builtin_nontemporal_store(p, out + (size_t)b * NPOS + i);  // step 0
        float sn, cn;
        __sincosf(p, &sn, &cn);
        mysc[s] = make_float2(sn, cn);
        sh.sc[0][i] = mysc[s];
        const size_t base = (size_t)b * (NPOS * 8) + (size_t)i * 8;
        const int4 j0 = *(const int4*)(conn + base);
        const int4 j1 = *(const int4*)(conn + base + 4);
        const float4 c0 = *(const float4*)(cpl + base);
        const float4 c1 = *(const float4*)(cpl + base + 4);
        rj[s][0] = j0.x; rj[s][1] = j0.y; rj[s][2] = j0.z; rj[s][3] = j0.w;
        rj[s][4] = j1.x; rj[s][5] = j1.y; rj[s][6] = j1.z; rj[s][7] = j1.w;
        rc[s][0] = c0.x; rc[s][1] = c0.y; rc[s][2] = c0.z; rc[s][3] = c0.w;
        rc[s][4] = c1.x; rc[s][5] = c1.y; rc[s][6] = c1.z; rc[s][7] = c1.w;
      }
    }
    float ep = 0.1f;
    for (int t = 0; t < STEPS; ++t) {
      __syncthreads();          // prior step's sc writes visible
      const int cur = t & 1;
      float* op = out + (size_t)(t + 1) * PH_STRIDE + (size_t)b * NPOS;
#pragma unroll
      for (int s = 0; s < 6; ++s) {
        const int i = tid + (s << 8);
        if (i < NPOS) {
          float ss = 0.f, cc = 0.f;
#pragma unroll
          for (int k = 0; k < 8; ++k) {
            const float2 v = sh.sc[cur][rj[s][k]];
            ss = fmaf(rc[s][k], v.x, ss);
            cc = fmaf(rc[s][k], v.y, cc);
          }
          const float np = myph[s] + ep * (mysc[s].y * ss - mysc[s].x * cc);
          myph[s] = np;
          __builtin_nontemporal_store(np, op + i);
          float sn, cn;
          __sincosf(np, &sn, &cn);
          mysc[s] = make_float2(sn, cn);
          sh.sc[cur ^ 1][i] = mysc[s];   // other buffer: no race with this step's gathers
        }
      }
      ep = ep * (1.0f - 0.02f * (float)t);  // ep -= 0.5*t*ep/25
    }
  }
}

extern "C" void kernel_launch(void* const* d_in, const int* in_sizes, int n_in,
                              void* d_out, int out_size, void* d_ws, size_t ws_size,
                              hipStream_t stream) {
  const float* input = (const float*)d_in[0];
  const float* ph0   = (const float*)d_in[1];
  const int*   conn  = (const int*)d_in[2];
  // d_in[3] = episodes (always 25)
  const float* w1 = (const float*)d_in[4];
  const float* b1 = (const float*)d_in[5];
  const float* w2 = (const float*)d_in[6];
  const float* b2 = (const float*)d_in[7];
  const float* w3 = (const float*)d_in[8];
  const float* b3 = (const float*)d_in[9];
  const float* fcw = (const float*)d_in[10];
  const float* fcb = (const float*)d_in[11];
  float* out = (float*)d_out;

  // workspace: Abuf bf16 [0, 42467328) | Wbuf bf16 [42467328, 48660480) | bar [48660480, +16)
  ushort* Abuf = (ushort*)d_ws;
  ushort* Wbuf = (ushort*)((char*)d_ws + 42467328);
  int*    bar  = (int*)((char*)d_ws + 48660480);

  hipMemsetAsync((void*)bar, 0, 16, stream);   // reset barrier counters each replay
  megakernel<<<NBLK, NTHR, 0, stream>>>(input, w1, b1, w2, b2, w3, b3, fcw, fcb,
                                        ph0, conn, Abuf, Wbuf, bar, out);
}

// Round 3
// 295.157 us; speedup vs baseline: 2.3392x; 2.3392x over previous
//
#include <hip/hip_runtime.h>
#include <hip/hip_bf16.h>

#define NPOS 1296              // 36*36 oscillators
#define BATCH 512
#define STEPS 25
#define PH_STRIDE (BATCH * NPOS)            // 663552
#define PH_TOTAL ((STEPS + 1) * PH_STRIDE)  // 17252352
#define FC_K 3456
#define FC_N 864
#define FC_NPAD 896
#define FC_M 6144
#define KT_ITERS 54            // FC_K / 64

typedef float f32x4 __attribute__((ext_vector_type(4)));
typedef __bf16 bf16x8 __attribute__((ext_vector_type(8)));
typedef ushort u16x8 __attribute__((ext_vector_type(8)));

__device__ __forceinline__ ushort f2bf(float f) {
  union { float f; unsigned u; } v; v.f = f;
  unsigned r = v.u + 0x7FFFu + ((v.u >> 16) & 1u);  // RNE
  return (ushort)(r >> 16);
}

__device__ __forceinline__ void async_copy16(void* lds, const void* g) {
  __builtin_amdgcn_global_load_lds(
      (const __attribute__((address_space(1))) unsigned*)g,
      (__attribute__((address_space(3))) unsigned*)lds, 16, 0, 0);
}
__device__ __forceinline__ void raw_barrier() { asm volatile("s_barrier" ::: "memory"); }
__device__ __forceinline__ void waitcnt_vm7() { asm volatile("s_waitcnt vmcnt(7)" ::: "memory"); }
__device__ __forceinline__ void waitcnt_vm0() { asm volatile("s_waitcnt vmcnt(0)" ::: "memory"); }

// ---------------- fused conv1(VALU) + conv2(MFMA) + conv3(MFMA+sigmoid) ----------------
// Weight fragments loaded DIRECTLY from w2/w3 global with transposed addressing
// (one-time per block, L2-broadcast) -> no wprep kernel, LDS stays 34880 B -> 4 blocks/CU.
// fcw->bf16 conversion for the gemm folded in as a grid-strided loop (no dependency on conv).
__global__ __launch_bounds__(256, 4) void conv_fused_kernel(
    const float* __restrict__ in, const float* __restrict__ w1, const float* __restrict__ b1,
    const float* __restrict__ w2, const float* __restrict__ b2,
    const float* __restrict__ w3, const float* __restrict__ b3,
    const float* __restrict__ fcw, ushort* __restrict__ Wbuf,
    ushort* __restrict__ aout) {
  __shared__ __align__(16) float sIn[18][40];          // input rows r0-3..r0+14, col x at x+2
  __shared__ __align__(16) ushort sC1[18][40][8];      // c1 rows r0-2..r0+13 (rows 16,17 zero)
  __shared__ __align__(16) ushort sC2[16][40][16];     // c2 rows r0-1..r0+12 (rows 14,15 zero)
  const int b = blockIdx.x, band = blockIdx.y, tid = threadIdx.x;
  const int r0 = band * 12;
  const int wave = tid >> 6, lane = tid & 63;
  const int quad = lane >> 4, l16 = lane & 15;

  // folded wcvt: fc_w f32 -> bf16, rows padded to FC_NPAD with zeros
  {
    const int lb = blockIdx.y * BATCH + blockIdx.x;     // 0..1535
    for (int idx = lb * 256 + tid; idx < FC_NPAD * FC_K; idx += 1536 * 256) {
      const int n = idx / FC_K;
      Wbuf[idx] = (n < FC_N) ? f2bf(fcw[idx]) : (ushort)0;
    }
  }
  {
    const uint4 zz = make_uint4(0, 0, 0, 0);
    for (int i = tid; i < 180; i += 256) ((uint4*)sIn)[i] = zz;
    for (int i = tid; i < 720; i += 256) ((uint4*)sC1)[i] = zz;
    for (int i = tid; i < 1280; i += 256) ((uint4*)sC2)[i] = zz;
  }
  // direct transposed weight-fragment loads (replaces wprep):
  // w2 fragment [co=l16][k=f*32+quad*8+j] = w2[(l16*8+j)*9 + s], s = 4f+quad (<9 else 0)
  bf16x8 w2f[3];
#pragma unroll
  for (int f = 0; f < 3; ++f) {
    const int s = 4 * f + quad;
    union { u16x8 u; bf16x8 bv; } cv;
#pragma unroll
    for (int j = 0; j < 8; ++j)
      cv.u[j] = (s < 9) ? f2bf(w2[(l16 * 8 + j) * 9 + s]) : (ushort)0;
    w2f[f] = cv.bv;
  }
  // w3 fragment [co=t*16+l16][k=f*32+quad*8+j] = w3[(co*16+ci)*9+s],
  //   s = 2f+(quad>>1) (<9 else 0), ci = (quad&1)*8+j
  bf16x8 w3f[2][5];
#pragma unroll
  for (int t = 0; t < 2; ++t)
#pragma unroll
    for (int f = 0; f < 5; ++f) {
      const int s = 2 * f + (quad >> 1);
      union { u16x8 u; bf16x8 bv; } cv;
#pragma unroll
      for (int j = 0; j < 8; ++j)
        cv.u[j] = (s < 9) ? f2bf(w3[((t * 16 + l16) * 16 + (quad & 1) * 8 + j) * 9 + s]) : (ushort)0;
      w3f[t][f] = cv.bv;
    }
  float b1v[8];
#pragma unroll
  for (int co = 0; co < 8; ++co) b1v[co] = b1[co];
  const float bias2 = b2[l16];
  const float bias3a = b3[l16], bias3b = b3[16 + l16];
  __syncthreads();
  for (int i = tid; i < 18 * 18; i += 256) {
    const int r = i / 18, c = i - r * 18;
    const int gy = r0 - 3 + r;
    if ((unsigned)gy < 36u)
      *(float2*)&sIn[r][2 + 2 * c] = *(const float2*)(in + (size_t)b * NPOS + gy * 36 + 2 * c);
  }
  __syncthreads();
  // conv1 (VALU; w1 uniform-address scalar loads)
  for (int i = tid; i < 16 * 36; i += 256) {
    const int lr = i / 36, x = i - lr * 36;
    float acc[8];
#pragma unroll
    for (int co = 0; co < 8; ++co) acc[co] = b1v[co];
#pragma unroll
    for (int s = 0; s < 9; ++s) {
      const int dy = s / 3, dx = s - 3 * dy;
      const float v = sIn[lr + dy][x + 1 + dx];
#pragma unroll
      for (int co = 0; co < 8; ++co) acc[co] = fmaf(w1[co * 9 + s], v, acc[co]);
    }
    const int g1 = r0 - 2 + lr;
    if ((unsigned)g1 < 36u) {
      uint4 pk;
      pk.x = (uint)f2bf(fmaxf(acc[0], 0.f)) | ((uint)f2bf(fmaxf(acc[1], 0.f)) << 16);
      pk.y = (uint)f2bf(fmaxf(acc[2], 0.f)) | ((uint)f2bf(fmaxf(acc[3], 0.f)) << 16);
      pk.z = (uint)f2bf(fmaxf(acc[4], 0.f)) | ((uint)f2bf(fmaxf(acc[5], 0.f)) << 16);
      pk.w = (uint)f2bf(fmaxf(acc[6], 0.f)) | ((uint)f2bf(fmaxf(acc[7], 0.f)) << 16);
      *(uint4*)&sC1[lr][x + 2][0] = pk;
    }
  }
  __syncthreads();
  // conv2 via MFMA: M=512 px, N=16 co, K=96 (72 real)
  for (int chunk = wave; chunk < 32; chunk += 4) {
    const int m = chunk * 16 + l16;
    const int oy = m / 36, x = m - oy * 36;
    f32x4 acc = {0.f, 0.f, 0.f, 0.f};
#pragma unroll
    for (int f = 0; f < 3; ++f) {
      const int s0 = 4 * f + quad;
      const int dy = s0 / 3, dx = s0 - 3 * dy;
      const bf16x8 af = *(const bf16x8*)&sC1[oy + dy][x + 1 + dx][0];
      acc = __builtin_amdgcn_mfma_f32_16x16x32_bf16(af, w2f[f], acc, 0, 0, 0);
    }
#pragma unroll
    for (int r = 0; r < 4; ++r) {
      const int px = chunk * 16 + quad * 4 + r;
      const int oy2 = px / 36, x2 = px - oy2 * 36;
      const int g2 = r0 - 1 + oy2;
      if (px < 504 && (unsigned)g2 < 36u)
        sC2[oy2][x2 + 2][l16] = f2bf(fmaxf(acc[r] + bias2, 0.f));
    }
  }
  __syncthreads();
  // conv3 via MFMA + sigmoid: M=432 px, N=32 co (2 tiles), K=160 (144 real)
  ushort* ob = aout + (size_t)b * (32 * NPOS) + r0 * 36;
  for (int chunk = wave; chunk < 27; chunk += 4) {
    const int m = chunk * 16 + l16;
    const int oy = m / 36, x = m - oy * 36;
    f32x4 acc0 = {0.f, 0.f, 0.f, 0.f}, acc1 = {0.f, 0.f, 0.f, 0.f};
#pragma unroll
    for (int f = 0; f < 5; ++f) {
      const int s0 = 2 * f + (quad >> 1);
      const int dy = s0 / 3, dx = s0 - 3 * dy;
      const bf16x8 af = *(const bf16x8*)&sC2[oy + dy][x + 1 + dx][(quad & 1) * 8];
      acc0 = __builtin_amdgcn_mfma_f32_16x16x32_bf16(af, w3f[0][f], acc0, 0, 0, 0);
      acc1 = __builtin_amdgcn_mfma_f32_16x16x32_bf16(af, w3f[1][f], acc1, 0, 0, 0);
    }
    const int pxb = chunk * 16 + quad * 4;
    ushort4 pk;
#pragma unroll
    for (int r = 0; r < 4; ++r)
      ((ushort*)&pk)[r] = f2bf(1.f / (1.f + __expf(-(acc0[r] + bias3a))));
    *(ushort4*)(ob + (size_t)l16 * NPOS + pxb) = pk;
#pragma unroll
    for (int r = 0; r < 4; ++r)
      ((ushort*)&pk)[r] = f2bf(1.f / (1.f + __expf(-(acc1[r] + bias3b))));
    *(ushort4*)(ob + (size_t)(16 + l16) * NPOS + pxb) = pk;
  }
}

// ---------------- bf16 NT GEMM: C[m][n] = sum_k A[m][k]*Bt[n][k] + bias[n] ----------------
// 96x128 block tile, 4 waves of 48x64 (3x4 acc). Double-buffered LDS tiles, raw s_barrier +
// s_waitcnt vmcnt(7) prefetch pipeline (tile kt+2 in flight during compute of tile kt).
// LDS cells XOR-swizzled -> conflict-free b128 reads with lane-linear global_load_lds dests.
__global__ __launch_bounds__(256) void gemm_kernel(
    const ushort* __restrict__ A, const ushort* __restrict__ Bt,
    const float* __restrict__ bias, float* __restrict__ C) {
  __shared__ __align__(16) ushort smem[2][14336];
  const int tid = threadIdx.x;
  const int lin = blockIdx.x;
  const int xcd = lin & 7, g = lin >> 3;           // 448 blocks
  const int bn = g % 7;
  const int bm = xcd + 8 * (g / 7);                // 0..63
  const int row0 = bm * 96, col0 = bn * 128;
  const int wave = tid >> 6, lane = tid & 63;
  const int wr = (wave >> 1) * 48, wc = (wave & 1) * 64;
  const int quad = lane >> 4, l16 = lane & 15;
  const int oswz = (quad ^ ((l16 >> 1) & 3)) * 8;  // swizzled octet offset for fragment reads
  f32x4 acc[3][4] = {};

  const int rr = lane >> 2;                              // row within chunk
  const int soct = ((lane & 3) ^ ((lane >> 3) & 3)) * 8; // source k-octet (elems)
  const ushort* gsrc[7];
  const ushort* ldst[7];
  {
    const int s = wave >> 1;  // slab this wave-pair stages
    if ((wave & 1) == 0) {
#pragma unroll
      for (int j = 0; j < 6; ++j) {
        gsrc[j] = A + ((size_t)row0 + j * 16 + rr) * FC_K + s * 32 + soct;
        ldst[j] = &smem[0][s * 3072 + j * 512];
      }
      gsrc[6] = Bt + ((size_t)col0 + rr) * FC_K + s * 32 + soct;
      ldst[6] = &smem[0][6144 + s * 4096];
    } else {
#pragma unroll
      for (int j = 0; j < 7; ++j) {
        gsrc[j] = Bt + ((size_t)col0 + (j + 1) * 16 + rr) * FC_K + s * 32 + soct;
        ldst[j] = &smem[0][6144 + s * 4096 + (j + 1) * 512];
      }
    }
  }
#pragma unroll
  for (int j = 0; j < 7; ++j) async_copy16((void*)ldst[j], gsrc[j]);
#pragma unroll
  for (int j = 0; j < 7; ++j) async_copy16((void*)(ldst[j] + 14336), gsrc[j] + 64);

  for (int kt = 0; kt < KT_ITERS; ++kt) {
    const int p = kt & 1;
    waitcnt_vm7();          // oldest 7 (this tile's chunks) complete; prefetch stays in flight
    raw_barrier();
    const ushort* base = &smem[p][0];
#pragma unroll
    for (int s = 0; s < 2; ++s) {
      bf16x8 af[3], bfr[4];
#pragma unroll
      for (int t = 0; t < 3; ++t)
        af[t] = *(const bf16x8*)(base + s * 3072 + (wr + t * 16 + l16) * 32 + oswz);
#pragma unroll
      for (int t = 0; t < 4; ++t)
        bfr[t] = *(const bf16x8*)(base + 6144 + s * 4096 + (wc + t * 16 + l16) * 32 + oswz);
#pragma unroll
      for (int tm = 0; tm < 3; ++tm)
#pragma unroll
        for (int tn = 0; tn < 4; ++tn)
          acc[tm][tn] = __builtin_amdgcn_mfma_f32_16x16x32_bf16(af[tm], bfr[tn], acc[tm][tn], 0, 0, 0);
    }
    raw_barrier();          // everyone done reading buffer p
    int kn = kt + 2;
    if (kn >= KT_ITERS) kn -= KT_ITERS;   // wrap: harmless extra tile keeps vmcnt uniform
    const int koff = kn * 64;
#pragma unroll
    for (int j = 0; j < 7; ++j) async_copy16((void*)(ldst[j] + p * 14336), gsrc[j] + koff);
  }
  waitcnt_vm0();            // drain dangling wrap copies before workgroup end

#pragma unroll
  for (int tn = 0; tn < 4; ++tn) {
    const int col = col0 + wc + tn * 16 + l16;
    if (col < FC_N) {
      const float bv = bias[col];
#pragma unroll
      for (int tm = 0; tm < 3; ++tm) {
#pragma unroll
        for (int r = 0; r < 4; ++r) {
          const int row = row0 + wr + tm * 16 + quad * 4 + r;
          C[(size_t)row * FC_N + col] = acc[tm][tn][r] + bv;
        }
      }
    }
  }
}

// ---------------- Kuramoto: one block (512 threads) per batch, 25 steps ----------------
// Phases + own sin/cos in registers; double-buffered sc -> ONE barrier per step.
__global__ __launch_bounds__(512) void kuramoto_kernel(
    const float* __restrict__ ph0, const int* __restrict__ conn,
    const float* __restrict__ cpl, float* __restrict__ out) {
  __shared__ float2 sc[2][NPOS];
  const int b = blockIdx.x, tid = threadIdx.x;
  int rj[3][8];
  float rc[3][8];
  float myph[3];
  float2 mysc[3];
#pragma unroll
  for (int s = 0; s < 3; ++s) {
    const int i = tid + s * 512;
    if (i < NPOS) {
      const float p = ph0[(size_t)b * NPOS + i];
      myph[s] = p;
      __builtin_nontemporal_store(p, out + (size_t)b * NPOS + i);  // step 0
      float sn, cn;
      __sincosf(p, &sn, &cn);
      mysc[s] = make_float2(sn, cn);
      sc[0][i] = mysc[s];
      const size_t base = (size_t)b * (NPOS * 8) + (size_t)i * 8;
      const int4 j0 = *(const int4*)(conn + base);
      const int4 j1 = *(const int4*)(conn + base + 4);
      const float4 c0 = *(const float4*)(cpl + base);
      const float4 c1 = *(const float4*)(cpl + base + 4);
      rj[s][0] = j0.x; rj[s][1] = j0.y; rj[s][2] = j0.z; rj[s][3] = j0.w;
      rj[s][4] = j1.x; rj[s][5] = j1.y; rj[s][6] = j1.z; rj[s][7] = j1.w;
      rc[s][0] = c0.x; rc[s][1] = c0.y; rc[s][2] = c0.z; rc[s][3] = c0.w;
      rc[s][4] = c1.x; rc[s][5] = c1.y; rc[s][6] = c1.z; rc[s][7] = c1.w;
    }
  }
  float ep = 0.1f;
  for (int t = 0; t < STEPS; ++t) {
    __syncthreads();          // step t-1's sc writes visible
    const int cur = t & 1;
    float* op = out + (size_t)(t + 1) * PH_STRIDE + (size_t)b * NPOS;
#pragma unroll
    for (int s = 0; s < 3; ++s) {
      const int i = tid + s * 512;
      if (i < NPOS) {
        float ss = 0.f, cc = 0.f;
#pragma unroll
        for (int k = 0; k < 8; ++k) {
          const float2 v = sc[cur][rj[s][k]];
          ss = fmaf(rc[s][k], v.x, ss);
          cc = fmaf(rc[s][k], v.y, cc);
        }
        const float np = myph[s] + ep * (mysc[s].y * ss - mysc[s].x * cc);
        myph[s] = np;
        __builtin_nontemporal_store(np, op + i);
        float sn, cn;
        __sincosf(np, &sn, &cn);
        mysc[s] = make_float2(sn, cn);
        sc[cur ^ 1][i] = mysc[s];   // other buffer: no race with this step's gathers
      }
    }
    ep = ep * (1.0f - 0.02f * (float)t);  // ep -= 0.5*t*ep/25
  }
}

extern "C" void kernel_launch(void* const* d_in, const int* in_sizes, int n_in,
                              void* d_out, int out_size, void* d_ws, size_t ws_size,
                              hipStream_t stream) {
  const float* input = (const float*)d_in[0];
  const float* ph0   = (const float*)d_in[1];
  const int*   conn  = (const int*)d_in[2];
  // d_in[3] = episodes (always 25)
  const float* w1 = (const float*)d_in[4];
  const float* b1 = (const float*)d_in[5];
  const float* w2 = (const float*)d_in[6];
  const float* b2 = (const float*)d_in[7];
  const float* w3 = (const float*)d_in[8];
  const float* b3 = (const float*)d_in[9];
  const float* fcw = (const float*)d_in[10];
  const float* fcb = (const float*)d_in[11];
  float* out = (float*)d_out;

  // workspace: Abuf bf16 [0, 42467328) | Wbuf bf16 [42467328, 48660480)
  ushort* Abuf = (ushort*)d_ws;
  ushort* Wbuf = (ushort*)((char*)d_ws + 42467328);
  float* fcout = out + PH_TOTAL;

  conv_fused_kernel<<<dim3(BATCH, 3), 256, 0, stream>>>(
      input, w1, b1, w2, b2, w3, b3, fcw, Wbuf, Abuf);
  gemm_kernel<<<448, 256, 0, stream>>>(Abuf, Wbuf, fcb, fcout);
  kuramoto_kernel<<<BATCH, 512, 0, stream>>>(ph0, conn, fcout, out);
}

// Round 4
// 247.976 us; speedup vs baseline: 2.7842x; 1.1903x over previous
//
#include <hip/hip_runtime.h>
#include <hip/hip_bf16.h>

#define NPOS 1296              // 36*36 oscillators
#define BATCH 512
#define STEPS 25
#define PH_STRIDE (BATCH * NPOS)            // 663552
#define PH_TOTAL ((STEPS + 1) * PH_STRIDE)  // 17252352
#define FC_K 3456
#define FC_N 864
#define FC_NPAD 896
#define KT_ITERS 54            // FC_K / 64

typedef float f32x4 __attribute__((ext_vector_type(4)));
typedef __bf16 bf16x8 __attribute__((ext_vector_type(8)));

__device__ __forceinline__ ushort f2bf(float f) {
  union { float f; unsigned u; } v; v.f = f;
  unsigned r = v.u + 0x7FFFu + ((v.u >> 16) & 1u);  // RNE
  return (ushort)(r >> 16);
}

__device__ __forceinline__ void async_copy16(void* lds, const void* g) {
  __builtin_amdgcn_global_load_lds(
      (const __attribute__((address_space(1))) unsigned*)g,
      (__attribute__((address_space(3))) unsigned*)lds, 16, 0, 0);
}
__device__ __forceinline__ void raw_barrier() { asm volatile("s_barrier" ::: "memory"); }
__device__ __forceinline__ void waitcnt_vm7() { asm volatile("s_waitcnt vmcnt(7)" ::: "memory"); }
__device__ __forceinline__ void waitcnt_vm0() { asm volatile("s_waitcnt vmcnt(0)" ::: "memory"); }

// ---------------- weight prep: w2/w3 -> MFMA-friendly [co][k] bf16 layouts ----------------
// Tiny (1 block, ~3 us) but keeps conv's fragment loads as 13 coalesced 16-B vector loads.
// (Round-3 lesson: direct scattered scalar loads in conv cost ~58 us in spills/latency.)
__global__ __launch_bounds__(256) void wprep_kernel(
    const float* __restrict__ w2, const float* __restrict__ w3,
    ushort* __restrict__ w2t, ushort* __restrict__ w3t) {
  const int tid = threadIdx.x;
  for (int i = tid; i < 16 * 96; i += 256) {
    const int co = i / 96, k = i - co * 96;
    const int s = k / 8, ci = k - s * 8;
    w2t[i] = (k < 72) ? f2bf(w2[(co * 8 + ci) * 9 + s]) : (ushort)0;
  }
  for (int i = tid; i < 32 * 160; i += 256) {
    const int co = i / 160, k = i - co * 160;
    const int s = k / 16, ci = k - s * 16;
    w3t[i] = (k < 144) ? f2bf(w3[(co * 16 + ci) * 9 + s]) : (ushort)0;
  }
}

// ---------------- fused conv1(VALU) + conv2(MFMA) + conv3(MFMA+sigmoid) ----------------
// fcw->bf16 conversion folded in as a grid-strided coalesced loop (no dependency on conv).
__global__ __launch_bounds__(256, 4) void conv_fused_kernel(
    const float* __restrict__ in, const float* __restrict__ w1, const float* __restrict__ b1,
    const ushort* __restrict__ w2t, const float* __restrict__ b2,
    const ushort* __restrict__ w3t, const float* __restrict__ b3,
    const float* __restrict__ fcw, ushort* __restrict__ Wbuf,
    ushort* __restrict__ aout) {
  __shared__ __align__(16) float sIn[18][40];          // input rows r0-3..r0+14, col x at x+2
  __shared__ __align__(16) ushort sC1[18][40][8];      // c1 rows r0-2..r0+13 (rows 16,17 zero)
  __shared__ __align__(16) ushort sC2[16][40][16];     // c2 rows r0-1..r0+12 (rows 14,15 zero)
  const int b = blockIdx.x, band = blockIdx.y, tid = threadIdx.x;
  const int r0 = band * 12;
  const int wave = tid >> 6, lane = tid & 63;
  const int quad = lane >> 4, l16 = lane & 15;

  // folded wcvt: fc_w f32 -> bf16, rows padded to FC_NPAD with zeros (coalesced)
  {
    const int lb = blockIdx.y * BATCH + blockIdx.x;     // 0..1535
    for (int idx = lb * 256 + tid; idx < FC_NPAD * FC_K; idx += 1536 * 256) {
      const int n = idx / FC_K;
      Wbuf[idx] = (n < FC_N) ? f2bf(fcw[idx]) : (ushort)0;
    }
  }
  {
    const uint4 zz = make_uint4(0, 0, 0, 0);
    for (int i = tid; i < 180; i += 256) ((uint4*)sIn)[i] = zz;
    for (int i = tid; i < 720; i += 256) ((uint4*)sC1)[i] = zz;
    for (int i = tid; i < 1280; i += 256) ((uint4*)sC2)[i] = zz;
  }
  __syncthreads();
  for (int i = tid; i < 18 * 18; i += 256) {
    const int r = i / 18, c = i - r * 18;
    const int gy = r0 - 3 + r;
    if ((unsigned)gy < 36u)
      *(float2*)&sIn[r][2 + 2 * c] = *(const float2*)(in + (size_t)b * NPOS + gy * 36 + 2 * c);
  }
  // coalesced MFMA weight-fragment loads (13 x 16 B per thread, L2-broadcast)
  bf16x8 w2f[3];
#pragma unroll
  for (int f = 0; f < 3; ++f)
    w2f[f] = *(const bf16x8*)(w2t + l16 * 96 + f * 32 + quad * 8);
  bf16x8 w3f[2][5];
#pragma unroll
  for (int t = 0; t < 2; ++t)
#pragma unroll
    for (int f = 0; f < 5; ++f)
      w3f[t][f] = *(const bf16x8*)(w3t + (t * 16 + l16) * 160 + f * 32 + quad * 8);
  const float bias2 = b2[l16];
  const float bias3a = b3[l16], bias3b = b3[16 + l16];
  __syncthreads();
  // conv1 (VALU; w1/b1 uniform-address scalar loads)
  for (int i = tid; i < 16 * 36; i += 256) {
    const int lr = i / 36, x = i - lr * 36;
    float acc[8];
#pragma unroll
    for (int co = 0; co < 8; ++co) acc[co] = b1[co];
#pragma unroll
    for (int s = 0; s < 9; ++s) {
      const int dy = s / 3, dx = s - 3 * dy;
      const float v = sIn[lr + dy][x + 1 + dx];
#pragma unroll
      for (int co = 0; co < 8; ++co) acc[co] = fmaf(w1[co * 9 + s], v, acc[co]);
    }
    const int g1 = r0 - 2 + lr;
    if ((unsigned)g1 < 36u) {
      uint4 pk;
      pk.x = (uint)f2bf(fmaxf(acc[0], 0.f)) | ((uint)f2bf(fmaxf(acc[1], 0.f)) << 16);
      pk.y = (uint)f2bf(fmaxf(acc[2], 0.f)) | ((uint)f2bf(fmaxf(acc[3], 0.f)) << 16);
      pk.z = (uint)f2bf(fmaxf(acc[4], 0.f)) | ((uint)f2bf(fmaxf(acc[5], 0.f)) << 16);
      pk.w = (uint)f2bf(fmaxf(acc[6], 0.f)) | ((uint)f2bf(fmaxf(acc[7], 0.f)) << 16);
      *(uint4*)&sC1[lr][x + 2][0] = pk;
    }
  }
  __syncthreads();
  // conv2 via MFMA: M=512 px, N=16 co, K=96 (72 real)
  for (int chunk = wave; chunk < 32; chunk += 4) {
    const int m = chunk * 16 + l16;
    const int oy = m / 36, x = m - oy * 36;
    f32x4 acc = {0.f, 0.f, 0.f, 0.f};
#pragma unroll
    for (int f = 0; f < 3; ++f) {
      const int s0 = 4 * f + quad;
      const int dy = s0 / 3, dx = s0 - 3 * dy;
      const bf16x8 af = *(const bf16x8*)&sC1[oy + dy][x + 1 + dx][0];
      acc = __builtin_amdgcn_mfma_f32_16x16x32_bf16(af, w2f[f], acc, 0, 0, 0);
    }
#pragma unroll
    for (int r = 0; r < 4; ++r) {
      const int px = chunk * 16 + quad * 4 + r;
      const int oy2 = px / 36, x2 = px - oy2 * 36;
      const int g2 = r0 - 1 + oy2;
      if (px < 504 && (unsigned)g2 < 36u)
        sC2[oy2][x2 + 2][l16] = f2bf(fmaxf(acc[r] + bias2, 0.f));
    }
  }
  __syncthreads();
  // conv3 via MFMA + sigmoid: M=432 px, N=32 co (2 tiles), K=160 (144 real)
  ushort* ob = aout + (size_t)b * (32 * NPOS) + r0 * 36;
  for (int chunk = wave; chunk < 27; chunk += 4) {
    const int m = chunk * 16 + l16;
    const int oy = m / 36, x = m - oy * 36;
    f32x4 acc0 = {0.f, 0.f, 0.f, 0.f}, acc1 = {0.f, 0.f, 0.f, 0.f};
#pragma unroll
    for (int f = 0; f < 5; ++f) {
      const int s0 = 2 * f + (quad >> 1);
      const int dy = s0 / 3, dx = s0 - 3 * dy;
      const bf16x8 af = *(const bf16x8*)&sC2[oy + dy][x + 1 + dx][(quad & 1) * 8];
      acc0 = __builtin_amdgcn_mfma_f32_16x16x32_bf16(af, w3f[0][f], acc0, 0, 0, 0);
      acc1 = __builtin_amdgcn_mfma_f32_16x16x32_bf16(af, w3f[1][f], acc1, 0, 0, 0);
    }
    const int pxb = chunk * 16 + quad * 4;
    ushort4 pk;
#pragma unroll
    for (int r = 0; r < 4; ++r)
      ((ushort*)&pk)[r] = f2bf(1.f / (1.f + __expf(-(acc0[r] + bias3a))));
    *(ushort4*)(ob + (size_t)l16 * NPOS + pxb) = pk;
#pragma unroll
    for (int r = 0; r < 4; ++r)
      ((ushort*)&pk)[r] = f2bf(1.f / (1.f + __expf(-(acc1[r] + bias3b))));
    *(ushort4*)(ob + (size_t)(16 + l16) * NPOS + pxb) = pk;
  }
}

// ---------------- bf16 NT GEMM: C[m][n] = sum_k A[m][k]*Bt[n][k] + bias[n] ----------------
// 96x128 block tile, 4 waves of 48x64 (3x4 acc). Double-buffered LDS tiles, raw s_barrier +
// s_waitcnt vmcnt(7) prefetch pipeline (tile kt+2 in flight during compute of tile kt).
// LDS cells XOR-swizzled -> conflict-free b128 reads with lane-linear global_load_lds dests.
__global__ __launch_bounds__(256) void gemm_kernel(
    const ushort* __restrict__ A, const ushort* __restrict__ Bt,
    const float* __restrict__ bias, float* __restrict__ C) {
  __shared__ __align__(16) ushort smem[2][14336];
  const int tid = threadIdx.x;
  const int lin = blockIdx.x;
  const int xcd = lin & 7, g = lin >> 3;           // 448 blocks
  const int bn = g % 7;
  const int bm = xcd + 8 * (g / 7);                // 0..63
  const int row0 = bm * 96, col0 = bn * 128;
  const int wave = tid >> 6, lane = tid & 63;
  const int wr = (wave >> 1) * 48, wc = (wave & 1) * 64;
  const int quad = lane >> 4, l16 = lane & 15;
  const int oswz = (quad ^ ((l16 >> 1) & 3)) * 8;  // swizzled octet offset for fragment reads
  f32x4 acc[3][4] = {};

  const int rr = lane >> 2;                              // row within chunk
  const int soct = ((lane & 3) ^ ((lane >> 3) & 3)) * 8; // source k-octet (elems)
  const ushort* gsrc[7];
  const ushort* ldst[7];
  {
    const int s = wave >> 1;  // slab this wave-pair stages
    if ((wave & 1) == 0) {
#pragma unroll
      for (int j = 0; j < 6; ++j) {
        gsrc[j] = A + ((size_t)row0 + j * 16 + rr) * FC_K + s * 32 + soct;
        ldst[j] = &smem[0][s * 3072 + j * 512];
      }
      gsrc[6] = Bt + ((size_t)col0 + rr) * FC_K + s * 32 + soct;
      ldst[6] = &smem[0][6144 + s * 4096];
    } else {
#pragma unroll
      for (int j = 0; j < 7; ++j) {
        gsrc[j] = Bt + ((size_t)col0 + (j + 1) * 16 + rr) * FC_K + s * 32 + soct;
        ldst[j] = &smem[0][6144 + s * 4096 + (j + 1) * 512];
      }
    }
  }
#pragma unroll
  for (int j = 0; j < 7; ++j) async_copy16((void*)ldst[j], gsrc[j]);
#pragma unroll
  for (int j = 0; j < 7; ++j) async_copy16((void*)(ldst[j] + 14336), gsrc[j] + 64);

  for (int kt = 0; kt < KT_ITERS; ++kt) {
    const int p = kt & 1;
    waitcnt_vm7();          // oldest 7 (this tile's chunks) complete; prefetch stays in flight
    raw_barrier();
    const ushort* base = &smem[p][0];
#pragma unroll
    for (int s = 0; s < 2; ++s) {
      bf16x8 af[3], bfr[4];
#pragma unroll
      for (int t = 0; t < 3; ++t)
        af[t] = *(const bf16x8*)(base + s * 3072 + (wr + t * 16 + l16) * 32 + oswz);
#pragma unroll
      for (int t = 0; t < 4; ++t)
        bfr[t] = *(const bf16x8*)(base + 6144 + s * 4096 + (wc + t * 16 + l16) * 32 + oswz);
#pragma unroll
      for (int tm = 0; tm < 3; ++tm)
#pragma unroll
        for (int tn = 0; tn < 4; ++tn)
          acc[tm][tn] = __builtin_amdgcn_mfma_f32_16x16x32_bf16(af[tm], bfr[tn], acc[tm][tn], 0, 0, 0);
    }
    raw_barrier();          // everyone done reading buffer p
    int kn = kt + 2;
    if (kn >= KT_ITERS) kn -= KT_ITERS;   // wrap: harmless extra tile keeps vmcnt uniform
    const int koff = kn * 64;
#pragma unroll
    for (int j = 0; j < 7; ++j) async_copy16((void*)(ldst[j] + p * 14336), gsrc[j] + koff);
  }
  waitcnt_vm0();            // drain dangling wrap copies before workgroup end

#pragma unroll
  for (int tn = 0; tn < 4; ++tn) {
    const int col = col0 + wc + tn * 16 + l16;
    if (col < FC_N) {
      const float bv = bias[col];
#pragma unroll
      for (int tm = 0; tm < 3; ++tm) {
#pragma unroll
        for (int r = 0; r < 4; ++r) {
          const int row = row0 + wr + tm * 16 + quad * 4 + r;
          C[(size_t)row * FC_N + col] = acc[tm][tn][r] + bv;
        }
      }
    }
  }
}

// ---------------- Kuramoto: one block (512 threads) per batch, 25 steps ----------------
// Phases + own sin/cos in registers; double-buffered sc -> ONE barrier per step.
__global__ __launch_bounds__(512) void kuramoto_kernel(
    const float* __restrict__ ph0, const int* __restrict__ conn,
    const float* __restrict__ cpl, float* __restrict__ out) {
  __shared__ float2 sc[2][NPOS];
  const int b = blockIdx.x, tid = threadIdx.x;
  int rj[3][8];
  float rc[3][8];
  float myph[3];
  float2 mysc[3];
#pragma unroll
  for (int s = 0; s < 3; ++s) {
    const int i = tid + s * 512;
    if (i < NPOS) {
      const float p = ph0[(size_t)b * NPOS + i];
      myph[s] = p;
      __builtin_nontemporal_store(p, out + (size_t)b * NPOS + i);  // step 0
      float sn, cn;
      __sincosf(p, &sn, &cn);
      mysc[s] = make_float2(sn, cn);
      sc[0][i] = mysc[s];
      const size_t base = (size_t)b * (NPOS * 8) + (size_t)i * 8;
      const int4 j0 = *(const int4*)(conn + base);
      const int4 j1 = *(const int4*)(conn + base + 4);
      const float4 c0 = *(const float4*)(cpl + base);
      const float4 c1 = *(const float4*)(cpl + base + 4);
      rj[s][0] = j0.x; rj[s][1] = j0.y; rj[s][2] = j0.z; rj[s][3] = j0.w;
      rj[s][4] = j1.x; rj[s][5] = j1.y; rj[s][6] = j1.z; rj[s][7] = j1.w;
      rc[s][0] = c0.x; rc[s][1] = c0.y; rc[s][2] = c0.z; rc[s][3] = c0.w;
      rc[s][4] = c1.x; rc[s][5] = c1.y; rc[s][6] = c1.z; rc[s][7] = c1.w;
    }
  }
  float ep = 0.1f;
  for (int t = 0; t < STEPS; ++t) {
    __syncthreads();          // step t-1's sc writes visible
    const int cur = t & 1;
    float* op = out + (size_t)(t + 1) * PH_STRIDE + (size_t)b * NPOS;
#pragma unroll
    for (int s = 0; s < 3; ++s) {
      const int i = tid + s * 512;
      if (i < NPOS) {
        float ss = 0.f, cc = 0.f;
#pragma unroll
        for (int k = 0; k < 8; ++k) {
          const float2 v = sc[cur][rj[s][k]];
          ss = fmaf(rc[s][k], v.x, ss);
          cc = fmaf(rc[s][k], v.y, cc);
        }
        const float np = myph[s] + ep * (mysc[s].y * ss - mysc[s].x * cc);
        myph[s] = np;
        __builtin_nontemporal_store(np, op + i);
        float sn, cn;
        __sincosf(np, &sn, &cn);
        mysc[s] = make_float2(sn, cn);
        sc[cur ^ 1][i] = mysc[s];   // other buffer: no race with this step's gathers
      }
    }
    ep = ep * (1.0f - 0.02f * (float)t);  // ep -= 0.5*t*ep/25
  }
}

extern "C" void kernel_launch(void* const* d_in, const int* in_sizes, int n_in,
                              void* d_out, int out_size, void* d_ws, size_t ws_size,
                              hipStream_t stream) {
  const float* input = (const float*)d_in[0];
  const float* ph0   = (const float*)d_in[1];
  const int*   conn  = (const int*)d_in[2];
  // d_in[3] = episodes (always 25)
  const float* w1 = (const float*)d_in[4];
  const float* b1 = (const float*)d_in[5];
  const float* w2 = (const float*)d_in[6];
  const float* b2 = (const float*)d_in[7];
  const float* w3 = (const float*)d_in[8];
  const float* b3 = (const float*)d_in[9];
  const float* fcw = (const float*)d_in[10];
  const float* fcb = (const float*)d_in[11];
  float* out = (float*)d_out;

  // workspace: Abuf bf16 [0, 42467328) | Wbuf bf16 [42467328, 48660480)
  //            w2t bf16 [48660480, +3072) | w3t bf16 [48663552, +10240)
  ushort* Abuf = (ushort*)d_ws;
  ushort* Wbuf = (ushort*)((char*)d_ws + 42467328);
  ushort* w2t  = (ushort*)((char*)d_ws + 48660480);
  ushort* w3t  = (ushort*)((char*)d_ws + 48663552);
  float* fcout = out + PH_TOTAL;

  wprep_kernel<<<1, 256, 0, stream>>>(w2, w3, w2t, w3t);
  conv_fused_kernel<<<dim3(BATCH, 3), 256, 0, stream>>>(
      input, w1, b1, w2t, b2, w3t, b3, fcw, Wbuf, Abuf);
  gemm_kernel<<<448, 256, 0, stream>>>(Abuf, Wbuf, fcb, fcout);
  kuramoto_kernel<<<BATCH, 512, 0, stream>>>(ph0, conn, fcout, out);
}

// Round 5
// 240.814 us; speedup vs baseline: 2.8670x; 1.0297x over previous
//
#include <hip/hip_runtime.h>
#include <hip/hip_bf16.h>

#define NPOS 1296              // 36*36 oscillators
#define BATCH 512
#define STEPS 25
#define PH_STRIDE (BATCH * NPOS)            // 663552
#define PH_TOTAL ((STEPS + 1) * PH_STRIDE)  // 17252352
#define FC_K 3456
#define FC_N 864
#define FC_NPAD 896
#define KT_ITERS 54            // FC_K / 64

typedef float f32x4 __attribute__((ext_vector_type(4)));
typedef __bf16 bf16x8 __attribute__((ext_vector_type(8)));

__device__ __forceinline__ ushort f2bf(float f) {
  union { float f; unsigned u; } v; v.f = f;
  unsigned r = v.u + 0x7FFFu + ((v.u >> 16) & 1u);  // RNE
  return (ushort)(r >> 16);
}

__device__ __forceinline__ void async_copy16(void* lds, const void* g) {
  __builtin_amdgcn_global_load_lds(
      (const __attribute__((address_space(1))) unsigned*)g,
      (__attribute__((address_space(3))) unsigned*)lds, 16, 0, 0);
}
__device__ __forceinline__ void raw_barrier() { asm volatile("s_barrier" ::: "memory"); }
__device__ __forceinline__ void waitcnt_vm7() { asm volatile("s_waitcnt vmcnt(7)" ::: "memory"); }
__device__ __forceinline__ void waitcnt_vm0() { asm volatile("s_waitcnt vmcnt(0)" ::: "memory"); }

// ---------------- weight prep: w2/w3 -> MFMA-friendly [co][k] bf16 layouts ----------------
__global__ __launch_bounds__(256) void wprep_kernel(
    const float* __restrict__ w2, const float* __restrict__ w3,
    ushort* __restrict__ w2t, ushort* __restrict__ w3t) {
  const int tid = threadIdx.x;
  for (int i = tid; i < 16 * 96; i += 256) {
    const int co = i / 96, k = i - co * 96;
    const int s = k / 8, ci = k - s * 8;
    w2t[i] = (k < 72) ? f2bf(w2[(co * 8 + ci) * 9 + s]) : (ushort)0;
  }
  for (int i = tid; i < 32 * 160; i += 256) {
    const int co = i / 160, k = i - co * 160;
    const int s = k / 16, ci = k - s * 16;
    w3t[i] = (k < 144) ? f2bf(w3[(co * 16 + ci) * 9 + s]) : (ushort)0;
  }
}

// ---------------- fused conv1(VALU) + conv2(MFMA) + conv3(MFMA+sigmoid) ----------------
// Full-image: one block per batch (512 blocks x 512 threads), whole 36x36 plane in LDS.
// vs banded version: no seam redundancy (was 1.33x conv1 / 1.5x input), 3x fewer
// LDS-zero/setup/barrier passes. LDS 79,040 B -> 2 blocks/CU = 16 waves/CU (same occ).
// Row convention: sIn[r] = input row r-1; sC1[r] = c1 row r-1; sC2[r] = c2 row r-1.
// fcw->bf16 for the gemm folded in as a grid-strided coalesced loop.
__global__ __launch_bounds__(512, 2) void conv_fused_kernel(
    const float* __restrict__ in, const float* __restrict__ w1, const float* __restrict__ b1,
    const ushort* __restrict__ w2t, const float* __restrict__ b2,
    const ushort* __restrict__ w3t, const float* __restrict__ b3,
    const float* __restrict__ fcw, ushort* __restrict__ Wbuf,
    ushort* __restrict__ aout) {
  __shared__ __align__(16) float sIn[38][40];          // 6080 B
  __shared__ __align__(16) ushort sC1[38][40][8];      // 24320 B
  __shared__ __align__(16) ushort sC2[38][40][16];     // 48640 B
  const int b = blockIdx.x, tid = threadIdx.x;
  const int wave = tid >> 6, lane = tid & 63;
  const int quad = lane >> 4, l16 = lane & 15;

  // folded wcvt: fc_w f32 -> bf16, rows padded to FC_NPAD with zeros (coalesced)
  for (int idx = b * 512 + tid; idx < FC_NPAD * FC_K; idx += BATCH * 512) {
    const int n = idx / FC_K;
    Wbuf[idx] = (n < FC_N) ? f2bf(fcw[idx]) : (ushort)0;
  }
  {
    const uint4 zz = make_uint4(0, 0, 0, 0);
    for (int i = tid; i < 380; i += 512) ((uint4*)sIn)[i] = zz;
    for (int i = tid; i < 1520; i += 512) ((uint4*)sC1)[i] = zz;
    for (int i = tid; i < 3040; i += 512) ((uint4*)sC2)[i] = zz;
  }
  __syncthreads();
  // stage input rows -1..36 (rows -1, 36 stay zero), col x at x+2
  for (int i = tid; i < 38 * 18; i += 512) {
    const int r = i / 18, c = i - r * 18;
    const int gy = r - 1;
    if ((unsigned)gy < 36u)
      *(float2*)&sIn[r][2 + 2 * c] = *(const float2*)(in + (size_t)b * NPOS + gy * 36 + 2 * c);
  }
  // coalesced MFMA weight-fragment loads (13 x 16 B per thread, L2-broadcast)
  bf16x8 w2f[3];
#pragma unroll
  for (int f = 0; f < 3; ++f)
    w2f[f] = *(const bf16x8*)(w2t + l16 * 96 + f * 32 + quad * 8);
  bf16x8 w3f[2][5];
#pragma unroll
  for (int t = 0; t < 2; ++t)
#pragma unroll
    for (int f = 0; f < 5; ++f)
      w3f[t][f] = *(const bf16x8*)(w3t + (t * 16 + l16) * 160 + f * 32 + quad * 8);
  const float bias2 = b2[l16];
  const float bias3a = b3[l16], bias3b = b3[16 + l16];
  __syncthreads();
  // conv1 (VALU; w1/b1 uniform-address scalar loads); out row y -> sC1[y+1]
  for (int i = tid; i < NPOS; i += 512) {
    const int y = i / 36, x = i - y * 36;
    float acc[8];
#pragma unroll
    for (int co = 0; co < 8; ++co) acc[co] = b1[co];
#pragma unroll
    for (int s = 0; s < 9; ++s) {
      const int dy = s / 3, dx = s - 3 * dy;
      const float v = sIn[y + dy][x + 1 + dx];   // input row y-1+dy, col x-1+dx
#pragma unroll
      for (int co = 0; co < 8; ++co) acc[co] = fmaf(w1[co * 9 + s], v, acc[co]);
    }
    uint4 pk;
    pk.x = (uint)f2bf(fmaxf(acc[0], 0.f)) | ((uint)f2bf(fmaxf(acc[1], 0.f)) << 16);
    pk.y = (uint)f2bf(fmaxf(acc[2], 0.f)) | ((uint)f2bf(fmaxf(acc[3], 0.f)) << 16);
    pk.z = (uint)f2bf(fmaxf(acc[4], 0.f)) | ((uint)f2bf(fmaxf(acc[5], 0.f)) << 16);
    pk.w = (uint)f2bf(fmaxf(acc[6], 0.f)) | ((uint)f2bf(fmaxf(acc[7], 0.f)) << 16);
    *(uint4*)&sC1[y + 1][x + 2][0] = pk;
  }
  __syncthreads();
  // conv2 via MFMA: M=1296 px (81 chunks over 8 waves), N=16 co, K=96 (72 real)
  for (int chunk = wave; chunk < 81; chunk += 8) {
    const int m = chunk * 16 + l16;
    const int oy = m / 36, x = m - oy * 36;
    f32x4 acc = {0.f, 0.f, 0.f, 0.f};
#pragma unroll
    for (int f = 0; f < 3; ++f) {
      const int s0 = 4 * f + quad;
      const int dy = s0 / 3, dx = s0 - 3 * dy;
      const bf16x8 af = *(const bf16x8*)&sC1[oy + dy][x + 1 + dx][0];
      acc = __builtin_amdgcn_mfma_f32_16x16x32_bf16(af, w2f[f], acc, 0, 0, 0);
    }
#pragma unroll
    for (int r = 0; r < 4; ++r) {
      const int px = chunk * 16 + quad * 4 + r;
      const int oy2 = px / 36, x2 = px - oy2 * 36;
      sC2[oy2 + 1][x2 + 2][l16] = f2bf(fmaxf(acc[r] + bias2, 0.f));
    }
  }
  __syncthreads();
  // conv3 via MFMA + sigmoid: M=1296 px, N=32 co (2 tiles), K=160 (144 real)
  ushort* ob = aout + (size_t)b * (32 * NPOS);
  for (int chunk = wave; chunk < 81; chunk += 8) {
    const int m = chunk * 16 + l16;
    const int oy = m / 36, x = m - oy * 36;
    f32x4 acc0 = {0.f, 0.f, 0.f, 0.f}, acc1 = {0.f, 0.f, 0.f, 0.f};
#pragma unroll
    for (int f = 0; f < 5; ++f) {
      const int s0 = 2 * f + (quad >> 1);
      const int dy = s0 / 3, dx = s0 - 3 * dy;
      const bf16x8 af = *(const bf16x8*)&sC2[oy + dy][x + 1 + dx][(quad & 1) * 8];
      acc0 = __builtin_amdgcn_mfma_f32_16x16x32_bf16(af, w3f[0][f], acc0, 0, 0, 0);
      acc1 = __builtin_amdgcn_mfma_f32_16x16x32_bf16(af, w3f[1][f], acc1, 0, 0, 0);
    }
    const int pxb = chunk * 16 + quad * 4;
    ushort4 pk;
#pragma unroll
    for (int r = 0; r < 4; ++r)
      ((ushort*)&pk)[r] = f2bf(1.f / (1.f + __expf(-(acc0[r] + bias3a))));
    *(ushort4*)(ob + (size_t)l16 * NPOS + pxb) = pk;
#pragma unroll
    for (int r = 0; r < 4; ++r)
      ((ushort*)&pk)[r] = f2bf(1.f / (1.f + __expf(-(acc1[r] + bias3b))));
    *(ushort4*)(ob + (size_t)(16 + l16) * NPOS + pxb) = pk;
  }
}

// ---------------- bf16 NT GEMM: C[m][n] = sum_k A[m][k]*Bt[n][k] + bias[n] ----------------
// 96x128 block tile, 4 waves of 48x64 (3x4 acc). Double-buffered LDS tiles, raw s_barrier +
// s_waitcnt vmcnt(7) prefetch pipeline (tile kt+2 in flight during compute of tile kt).
// LDS cells XOR-swizzled -> conflict-free b128 reads with lane-linear global_load_lds dests.
__global__ __launch_bounds__(256) void gemm_kernel(
    const ushort* __restrict__ A, const ushort* __restrict__ Bt,
    const float* __restrict__ bias, float* __restrict__ C) {
  __shared__ __align__(16) ushort smem[2][14336];
  const int tid = threadIdx.x;
  const int lin = blockIdx.x;
  const int xcd = lin & 7, g = lin >> 3;           // 448 blocks
  const int bn = g % 7;
  const int bm = xcd + 8 * (g / 7);                // 0..63
  const int row0 = bm * 96, col0 = bn * 128;
  const int wave = tid >> 6, lane = tid & 63;
  const int wr = (wave >> 1) * 48, wc = (wave & 1) * 64;
  const int quad = lane >> 4, l16 = lane & 15;
  const int oswz = (quad ^ ((l16 >> 1) & 3)) * 8;  // swizzled octet offset for fragment reads
  f32x4 acc[3][4] = {};

  const int rr = lane >> 2;                              // row within chunk
  const int soct = ((lane & 3) ^ ((lane >> 3) & 3)) * 8; // source k-octet (elems)
  const ushort* gsrc[7];
  const ushort* ldst[7];
  {
    const int s = wave >> 1;  // slab this wave-pair stages
    if ((wave & 1) == 0) {
#pragma unroll
      for (int j = 0; j < 6; ++j) {
        gsrc[j] = A + ((size_t)row0 + j * 16 + rr) * FC_K + s * 32 + soct;
        ldst[j] = &smem[0][s * 3072 + j * 512];
      }
      gsrc[6] = Bt + ((size_t)col0 + rr) * FC_K + s * 32 + soct;
      ldst[6] = &smem[0][6144 + s * 4096];
    } else {
#pragma unroll
      for (int j = 0; j < 7; ++j) {
        gsrc[j] = Bt + ((size_t)col0 + (j + 1) * 16 + rr) * FC_K + s * 32 + soct;
        ldst[j] = &smem[0][6144 + s * 4096 + (j + 1) * 512];
      }
    }
  }
#pragma unroll
  for (int j = 0; j < 7; ++j) async_copy16((void*)ldst[j], gsrc[j]);
#pragma unroll
  for (int j = 0; j < 7; ++j) async_copy16((void*)(ldst[j] + 14336), gsrc[j] + 64);

  for (int kt = 0; kt < KT_ITERS; ++kt) {
    const int p = kt & 1;
    waitcnt_vm7();          // oldest 7 (this tile's chunks) complete; prefetch stays in flight
    raw_barrier();
    const ushort* base = &smem[p][0];
#pragma unroll
    for (int s = 0; s < 2; ++s) {
      bf16x8 af[3], bfr[4];
#pragma unroll
      for (int t = 0; t < 3; ++t)
        af[t] = *(const bf16x8*)(base + s * 3072 + (wr + t * 16 + l16) * 32 + oswz);
#pragma unroll
      for (int t = 0; t < 4; ++t)
        bfr[t] = *(const bf16x8*)(base + 6144 + s * 4096 + (wc + t * 16 + l16) * 32 + oswz);
#pragma unroll
      for (int tm = 0; tm < 3; ++tm)
#pragma unroll
        for (int tn = 0; tn < 4; ++tn)
          acc[tm][tn] = __builtin_amdgcn_mfma_f32_16x16x32_bf16(af[tm], bfr[tn], acc[tm][tn], 0, 0, 0);
    }
    raw_barrier();          // everyone done reading buffer p
    int kn = kt + 2;
    if (kn >= KT_ITERS) kn -= KT_ITERS;   // wrap: harmless extra tile keeps vmcnt uniform
    const int koff = kn * 64;
#pragma unroll
    for (int j = 0; j < 7; ++j) async_copy16((void*)(ldst[j] + p * 14336), gsrc[j] + koff);
  }
  waitcnt_vm0();            // drain dangling wrap copies before workgroup end

#pragma unroll
  for (int tn = 0; tn < 4; ++tn) {
    const int col = col0 + wc + tn * 16 + l16;
    if (col < FC_N) {
      const float bv = bias[col];
#pragma unroll
      for (int tm = 0; tm < 3; ++tm) {
#pragma unroll
        for (int r = 0; r < 4; ++r) {
          const int row = row0 + wr + tm * 16 + quad * 4 + r;
          C[(size_t)row * FC_N + col] = acc[tm][tn][r] + bv;
        }
      }
    }
  }
}

// ---------------- Kuramoto: one block (512 threads) per batch, 25 steps ----------------
// Phases + own sin/cos in registers; double-buffered sc -> ONE barrier per step.
__global__ __launch_bounds__(512) void kuramoto_kernel(
    const float* __restrict__ ph0, const int* __restrict__ conn,
    const float* __restrict__ cpl, float* __restrict__ out) {
  __shared__ float2 sc[2][NPOS];
  const int b = blockIdx.x, tid = threadIdx.x;
  int rj[3][8];
  float rc[3][8];
  float myph[3];
  float2 mysc[3];
#pragma unroll
  for (int s = 0; s < 3; ++s) {
    const int i = tid + s * 512;
    if (i < NPOS) {
      const float p = ph0[(size_t)b * NPOS + i];
      myph[s] = p;
      __builtin_nontemporal_store(p, out + (size_t)b * NPOS + i);  // step 0
      float sn, cn;
      __sincosf(p, &sn, &cn);
      mysc[s] = make_float2(sn, cn);
      sc[0][i] = mysc[s];
      const size_t base = (size_t)b * (NPOS * 8) + (size_t)i * 8;
      const int4 j0 = *(const int4*)(conn + base);
      const int4 j1 = *(const int4*)(conn + base + 4);
      const float4 c0 = *(const float4*)(cpl + base);
      const float4 c1 = *(const float4*)(cpl + base + 4);
      rj[s][0] = j0.x; rj[s][1] = j0.y; rj[s][2] = j0.z; rj[s][3] = j0.w;
      rj[s][4] = j1.x; rj[s][5] = j1.y; rj[s][6] = j1.z; rj[s][7] = j1.w;
      rc[s][0] = c0.x; rc[s][1] = c0.y; rc[s][2] = c0.z; rc[s][3] = c0.w;
      rc[s][4] = c1.x; rc[s][5] = c1.y; rc[s][6] = c1.z; rc[s][7] = c1.w;
    }
  }
  float ep = 0.1f;
  for (int t = 0; t < STEPS; ++t) {
    __syncthreads();          // step t-1's sc writes visible
    const int cur = t & 1;
    float* op = out + (size_t)(t + 1) * PH_STRIDE + (size_t)b * NPOS;
#pragma unroll
    for (int s = 0; s < 3; ++s) {
      const int i = tid + s * 512;
      if (i < NPOS) {
        float ss = 0.f, cc = 0.f;
#pragma unroll
        for (int k = 0; k < 8; ++k) {
          const float2 v = sc[cur][rj[s][k]];
          ss = fmaf(rc[s][k], v.x, ss);
          cc = fmaf(rc[s][k], v.y, cc);
        }
        const float np = myph[s] + ep * (mysc[s].y * ss - mysc[s].x * cc);
        myph[s] = np;
        __builtin_nontemporal_store(np, op + i);
        float sn, cn;
        __sincosf(np, &sn, &cn);
        mysc[s] = make_float2(sn, cn);
        sc[cur ^ 1][i] = mysc[s];   // other buffer: no race with this step's gathers
      }
    }
    ep = ep * (1.0f - 0.02f * (float)t);  // ep -= 0.5*t*ep/25
  }
}

extern "C" void kernel_launch(void* const* d_in, const int* in_sizes, int n_in,
                              void* d_out, int out_size, void* d_ws, size_t ws_size,
                              hipStream_t stream) {
  const float* input = (const float*)d_in[0];
  const float* ph0   = (const float*)d_in[1];
  const int*   conn  = (const int*)d_in[2];
  // d_in[3] = episodes (always 25)
  const float* w1 = (const float*)d_in[4];
  const float* b1 = (const float*)d_in[5];
  const float* w2 = (const float*)d_in[6];
  const float* b2 = (const float*)d_in[7];
  const float* w3 = (const float*)d_in[8];
  const float* b3 = (const float*)d_in[9];
  const float* fcw = (const float*)d_in[10];
  const float* fcb = (const float*)d_in[11];
  float* out = (float*)d_out;

  // workspace: Abuf bf16 [0, 42467328) | Wbuf bf16 [42467328, 48660480)
  //            w2t bf16 [48660480, +3072) | w3t bf16 [48663552, +10240)
  ushort* Abuf = (ushort*)d_ws;
  ushort* Wbuf = (ushort*)((char*)d_ws + 42467328);
  ushort* w2t  = (ushort*)((char*)d_ws + 48660480);
  ushort* w3t  = (ushort*)((char*)d_ws + 48663552);
  float* fcout = out + PH_TOTAL;

  wprep_kernel<<<1, 256, 0, stream>>>(w2, w3, w2t, w3t);
  conv_fused_kernel<<<BATCH, 512, 0, stream>>>(
      input, w1, b1, w2t, b2, w3t, b3, fcw, Wbuf, Abuf);
  gemm_kernel<<<448, 256, 0, stream>>>(Abuf, Wbuf, fcb, fcout);
  kuramoto_kernel<<<BATCH, 512, 0, stream>>>(ph0, conn, fcout, out);
}